// Round 1
// baseline (639.951 us; speedup 1.0000x reference)
//
#include <hip/hip_runtime.h>
#include <hip/hip_bf16.h>

#define B_ 2048
#define D_ 512
#define N_ 100000
#define F_ 64
#define NEGV (-1000000.0f)

typedef __bf16 bfx8 __attribute__((ext_vector_type(8)));
typedef float f32x4 __attribute__((ext_vector_type(4)));
typedef unsigned short u16x8 __attribute__((ext_vector_type(8)));

static __device__ __forceinline__ unsigned short f2bf(float f) {
  unsigned u = __float_as_uint(f);
  unsigned r = (u + 0x7fffu + ((u >> 16) & 1u)) >> 16;
  return (unsigned short)r;
}
static __device__ __forceinline__ float bf2f(unsigned short u) {
  return __uint_as_float(((unsigned)u) << 16);
}

static __device__ __forceinline__ void async_copy16(const void* g, void* l) {
  __builtin_amdgcn_global_load_lds((const __attribute__((address_space(1))) void*)g,
                                   (__attribute__((address_space(3))) void*)l, 16, 0, 0);
}

// ---- targets (fp32, matches reference einsum) + out init -------------------
__global__ void targets_init(const float* __restrict__ q, const float* __restrict__ rhs,
                             const int* __restrict__ queries, float* __restrict__ targets,
                             float* __restrict__ out) {
  int b = blockIdx.x * 4 + (threadIdx.x >> 6);
  int lane = threadIdx.x & 63;
  int p = queries[b * 3 + 2];
  float s = 0.f;
  for (int d = lane; d < D_; d += 64) s += q[b * D_ + d] * rhs[(size_t)d * N_ + p];
  for (int off = 32; off; off >>= 1) s += __shfl_down(s, off, 64);
  if (lane == 0) { targets[b] = s; out[b] = 1.0f; }
}

// ---- q fp32 -> bf16 --------------------------------------------------------
__global__ void convert_q(const float* __restrict__ q, unsigned short* __restrict__ qb) {
  int i = blockIdx.x * blockDim.x + threadIdx.x;  // over B*D/4
  const float4* q4 = (const float4*)q;
  float4 v = q4[i];
  ushort4 o;
  o.x = f2bf(v.x); o.y = f2bf(v.y); o.z = f2bf(v.z); o.w = f2bf(v.w);
  ((ushort4*)qb)[i] = o;
}

// ---- rhs (D x N fp32) -> rt (N x D bf16), 64x64 LDS tile transpose ---------
__global__ void transpose_rhs(const float* __restrict__ rhs, unsigned short* __restrict__ rt) {
  __shared__ float tile[64][65];
  int n0 = blockIdx.x * 64, d0 = blockIdx.y * 64;
  int c = threadIdx.x & 63, r4 = threadIdx.x >> 6;
#pragma unroll
  for (int p = 0; p < 16; ++p) {
    int d = r4 + p * 4;
    int n = n0 + c;
    if (n < N_) tile[d][c] = rhs[(size_t)(d0 + d) * N_ + n];
  }
  __syncthreads();
#pragma unroll
  for (int p = 0; p < 16; ++p) {
    int nl = r4 + p * 4;
    int n = n0 + nl;
    if (n < N_) rt[(size_t)n * D_ + d0 + c] = f2bf(tile[c][nl]);
  }
}

// ---- main: bf16 MFMA GEMM -> per-row count of (score >= target) ------------
__global__ void __launch_bounds__(256) gemm_count(
    const unsigned short* __restrict__ qb,   // B x D bf16
    const unsigned short* __restrict__ rt,   // N x D bf16 (transposed rhs)
    const float* __restrict__ targets,
    float* __restrict__ out) {
  __shared__ unsigned short As[128 * 32];   // [m][k] row-major
  __shared__ unsigned short Bs[128 * 32];   // [n][k] row-major
  __shared__ float sT[128];
  __shared__ int cnt[128];

  int tid = threadIdx.x;
  int m0 = blockIdx.x * 128;
  int n0 = blockIdx.y * 128;

  if (tid < 128) { sT[tid] = targets[m0 + tid]; cnt[tid] = 0; }

  int w = tid >> 6, lane = tid & 63;
  int mw = (w & 1) * 64, nw = (w >> 1) * 64;
  int quad = lane >> 4, l16 = lane & 15;

  f32x4 acc[4][4];
  f32x4 z = {0.f, 0.f, 0.f, 0.f};
#pragma unroll
  for (int i = 0; i < 4; ++i)
#pragma unroll
    for (int j = 0; j < 4; ++j) acc[i][j] = z;

  for (int kt = 0; kt < 16; ++kt) {
    int k0 = kt * 32;
    __syncthreads();
#pragma unroll
    for (int i = 0; i < 2; ++i) {
      int c = i * 256 + tid;             // chunk 0..511 (8 bf16 each)
      int m = c >> 2, k8 = (c & 3) * 8;
      const unsigned short* gp = qb + (size_t)(m0 + m) * D_ + k0 + k8;
      async_copy16(gp, As + c * 8);
    }
#pragma unroll
    for (int i = 0; i < 2; ++i) {
      int c = i * 256 + tid;
      int n = c >> 2, k8 = (c & 3) * 8;
      int ng = n0 + n; if (ng > N_ - 1) ng = N_ - 1;   // clamp tail
      const unsigned short* gp = rt + (size_t)ng * D_ + k0 + k8;
      async_copy16(gp, Bs + c * 8);
    }
    __syncthreads();

    bfx8 a[4], b[4];
#pragma unroll
    for (int mi = 0; mi < 4; ++mi) {
      int m = mw + mi * 16 + l16;
      u16x8 au = *(const u16x8*)(As + m * 32 + quad * 8);
      a[mi] = __builtin_bit_cast(bfx8, au);
    }
#pragma unroll
    for (int ni = 0; ni < 4; ++ni) {
      int n = nw + ni * 16 + l16;
      u16x8 bu = *(const u16x8*)(Bs + n * 32 + quad * 8);
      b[ni] = __builtin_bit_cast(bfx8, bu);
    }
#pragma unroll
    for (int mi = 0; mi < 4; ++mi)
#pragma unroll
      for (int ni = 0; ni < 4; ++ni)
        acc[mi][ni] = __builtin_amdgcn_mfma_f32_16x16x32_bf16(a[mi], b[ni], acc[mi][ni], 0, 0, 0);
  }

  // epilogue: compare vs target, accumulate counts
#pragma unroll
  for (int mi = 0; mi < 4; ++mi) {
#pragma unroll
    for (int reg = 0; reg < 4; ++reg) {
      int rl = mw + mi * 16 + quad * 4 + reg;   // C/D: row=(lane>>4)*4+reg
      float t = sT[rl];
      int c = 0;
#pragma unroll
      for (int ni = 0; ni < 4; ++ni) {
        int col = n0 + nw + ni * 16 + l16;      // C/D: col=lane&15
        if (col < N_ && acc[mi][ni][reg] >= t) c++;
      }
      if (c) atomicAdd(&cnt[rl], c);
    }
  }
  __syncthreads();
  if (tid < 128 && cnt[tid]) atomicAdd(&out[m0 + tid], (float)cnt[tid]);
}

// ---- corrections: subtract filtered/true positions that were counted -------
__global__ void corrections(const unsigned short* __restrict__ qb,
                            const unsigned short* __restrict__ rt,
                            const int* __restrict__ queries,
                            const int* __restrict__ filt,
                            const float* __restrict__ targets,
                            float* __restrict__ out) {
  int b = blockIdx.x;
  int tid = threadIdx.x;  // 128
  __shared__ int idx[F_ + 1];
  __shared__ float red[128];
  if (tid < F_) idx[tid] = filt[b * F_ + tid];
  if (tid == F_) idx[F_] = queries[b * 3 + 2];
  __syncthreads();
  float corr = 0.f;
  float t = targets[b];
  if (tid <= F_) {
    int p = idx[tid];
    bool uniq = true;
    for (int j = 0; j < tid; ++j)
      if (idx[j] == p) uniq = false;
    if (uniq) {
      float s = 0.f;
      const u16x8* qr = (const u16x8*)(qb + (size_t)b * D_);
      const u16x8* rr = (const u16x8*)(rt + (size_t)p * D_);
      for (int i = 0; i < D_ / 8; ++i) {
        u16x8 qv = qr[i], rv = rr[i];
#pragma unroll
        for (int j = 0; j < 8; ++j) s += bf2f(qv[j]) * bf2f(rv[j]);
      }
      corr = (NEGV >= t ? 1.f : 0.f) - (s >= t ? 1.f : 0.f);
    }
  }
  red[tid] = corr;
  __syncthreads();
  if (tid == 0) {
    float tot = 0.f;
    for (int i = 0; i < 128; ++i) tot += red[i];
    if (tot != 0.f) atomicAdd(&out[b], tot);
  }
}

// ---- fallback (ws too small): fp32 vector path, slow but correct -----------
__global__ void fallback_count(const float* __restrict__ q, const float* __restrict__ rhs,
                               const int* __restrict__ queries, const int* __restrict__ filt,
                               const float* __restrict__ targets, float* __restrict__ out) {
  int b = blockIdx.y;
  int n = blockIdx.x * 256 + threadIdx.x;
  __shared__ float qs[D_];
  __shared__ int idx[F_ + 1];
  __shared__ int cnt;
  for (int d = threadIdx.x; d < D_; d += 256) qs[d] = q[b * D_ + d];
  if (threadIdx.x < F_) idx[threadIdx.x] = filt[b * F_ + threadIdx.x];
  if (threadIdx.x == F_) idx[F_] = queries[b * 3 + 2];
  if (threadIdx.x == 0) cnt = 0;
  __syncthreads();
  if (n < N_) {
    float t = targets[b];
    float s = 0.f;
    for (int d = 0; d < D_; ++d) s += qs[d] * rhs[(size_t)d * N_ + n];
    bool member = false;
    for (int j = 0; j <= F_; ++j)
      if (idx[j] == n) member = true;
    float sv = member ? NEGV : s;
    if (sv >= t) atomicAdd(&cnt, 1);
  }
  __syncthreads();
  if (threadIdx.x == 0 && cnt) atomicAdd(&out[b], (float)cnt);
}

extern "C" void kernel_launch(void* const* d_in, const int* in_sizes, int n_in,
                              void* d_out, int out_size, void* d_ws, size_t ws_size,
                              hipStream_t stream) {
  const float* q = (const float*)d_in[0];
  const float* rhs = (const float*)d_in[1];
  const int* queries = (const int*)d_in[2];
  const int* filt = (const int*)d_in[3];
  float* out = (float*)d_out;

  char* wsb = (char*)d_ws;
  float* targets = (float*)wsb;                                   // 8 KB
  unsigned short* qb = (unsigned short*)(wsb + 8192);             // 2 MB
  unsigned short* rt = (unsigned short*)(wsb + 8192 + (size_t)B_ * D_ * 2);  // 102.4 MB
  size_t need = 8192 + (size_t)B_ * D_ * 2 + (size_t)N_ * D_ * 2;

  targets_init<<<B_ / 4, 256, 0, stream>>>(q, rhs, queries, targets, out);

  if (ws_size >= need) {
    convert_q<<<(B_ * D_ / 4) / 256, 256, 0, stream>>>(q, qb);
    transpose_rhs<<<dim3((N_ + 63) / 64, D_ / 64), 256, 0, stream>>>(rhs, rt);
    gemm_count<<<dim3(B_ / 128, (N_ + 127) / 128), 256, 0, stream>>>(qb, rt, targets, out);
    corrections<<<B_, 128, 0, stream>>>(qb, rt, queries, filt, targets, out);
  } else {
    fallback_count<<<dim3((N_ + 255) / 256, B_), 256, 0, stream>>>(q, rhs, queries, filt, targets, out);
  }
}